// Round 9
// baseline (21.901 us; speedup 1.0000x reference)
//
#include <hip/hip_runtime.h>

// Problem constants (from reference)
#define HH 96
#define WW 96
#define CH 64
#define NHEADS 4
#define DHEAD 16
#define RAD 3
#define BATCH 2
#define PLANE (HH * WW)

// Tiling: 8x8 positions/block, 512 threads = 64 pos x 4 cg x 2 neighbor-halves.
// LDS unit per (pixel, cg): uint4 = [k01|k23|v01|v23] fp16 -> ONE ds_read_b128
// per neighbor. Pixel stride 5 units (80B).
#define TS 8
#define HS (TS + 2 * RAD)       // 14 halo side
#define HP (HS * HS)            // 196 halo pixels
#define PUNITS 5                // uint4 per pixel: 4 cg units + 1 pad
#define TPD (HH / TS)           // 12
#define TILES (TPD * TPD)       // 144 per (b,head) slab

typedef _Float16 h2 __attribute__((ext_vector_type(2)));
union H2U { unsigned int u; h2 h; };

// DPP quad_perm cross-lane add (VALU pipe, not DS)
template <int CTRL>
__device__ __forceinline__ float qperm(float x) {
    return __int_as_float(
        __builtin_amdgcn_mov_dpp(__float_as_int(x), CTRL, 0xF, 0xF, true));
}

__device__ __forceinline__ float dot4(unsigned k01, unsigned k23, h2 q01, h2 q23) {
    H2U a, b; a.u = k01; b.u = k23;
#if __has_builtin(__builtin_amdgcn_fdot2)
    return __builtin_amdgcn_fdot2(a.h, q01,
           __builtin_amdgcn_fdot2(b.h, q23, 0.0f, false), false);
#else
    float s = (float)a.h.x * (float)q01.x;
    s = fmaf((float)a.h.y, (float)q01.y, s);
    s = fmaf((float)b.h.x, (float)q23.x, s);
    s = fmaf((float)b.h.y, (float)q23.y, s);
    return s;
#endif
}

// Unrolled neighbor range [I0, I1): i -> dy = i/7-3, dx = i%7-3 (compile-time)
template <bool INTERIOR, int I0, int I1>
__device__ __forceinline__ void nb_range(
    const uint4* __restrict__ lds4, int lbase,
    h2 q01, h2 q23, int h, int w,
    float& ssum, float& o0, float& o1, float& o2, float& o3)
{
#pragma unroll
    for (int i = I0; i < I1; ++i) {
        const int dy = i / 7 - RAD;
        const int dx = i % 7 - RAD;
        const uint4 kv = lds4[lbase + (dy * HS + dx) * PUNITS];
        float s = dot4(kv.x, kv.y, q01, q23);
        s += qperm<0xB1>(s);   // xor 1 (within cg quad)
        s += qperm<0x4E>(s);   // xor 2
        if constexpr (!INTERIOR) {
            const bool ok = ((unsigned)(h + dy) < (unsigned)HH) &&
                            ((unsigned)(w + dx) < (unsigned)WW);
            s = ok ? s : -1000.f;
        }
        const float p = __builtin_amdgcn_exp2f(s);
        ssum += p;
        H2U v01, v23; v01.u = kv.z; v23.u = kv.w;
        o0 = fmaf(p, (float)v01.h.x, o0);
        o1 = fmaf(p, (float)v01.h.y, o1);
        o2 = fmaf(p, (float)v23.h.x, o2);
        o3 = fmaf(p, (float)v23.h.y, o3);
    }
}

template <bool INTERIOR>
__device__ __forceinline__ void tile_body(
    const float* __restrict__ q, const float* __restrict__ k,
    const float* __restrict__ v, float* __restrict__ out,
    uint4* __restrict__ lds4, int b, int head, int h0, int w0)
{
    const int tid = threadIdx.x;              // 0..511
    const int cg  = tid & 3;                  // channel group (bits 0-1)
    const int ns  = (tid >> 2) & 1;           // neighbor half (bit 2)
    const int pos = tid >> 3;                 // 0..63
    const int px  = pos & 7, py = pos >> 3;
    const int h = h0 + py, w = w0 + px;

    // q for this thread's 4 channels, pre-scaled by 0.25*log2(e)
    const float QS = 0.25f * 1.4426950408889634f;
    const int qoff = (b * CH + head * DHEAD + cg * 4) * PLANE + h * WW + w;
    h2 q01, q23;
    q01.x = (_Float16)(q[qoff]             * QS);
    q01.y = (_Float16)(q[qoff +     PLANE] * QS);
    q23.x = (_Float16)(q[qoff + 2 * PLANE] * QS);
    q23.y = (_Float16)(q[qoff + 3 * PLANE] * QS);

    // ---- Stage halo: 784 (pix,cg) uint4 units, 512 threads, 2 rounds ----
    {
        const float* kbp = k + (size_t)(b * CH + head * DHEAD) * PLANE;
        const float* vbp = v + (size_t)(b * CH + head * DHEAD) * PLANE;
#pragma unroll
        for (int r = 0; r < 2; ++r) {
            const int u = tid + r * 512;
            if (r == 0 || u < HP * 4) {       // 784
                const int ucg = u & 3;
                const int pix = u >> 2;
                int gh = h0 - RAD + pix / HS;
                int gw = w0 - RAD + pix % HS;
                if constexpr (!INTERIOR) {
                    gh = min(max(gh, 0), HH - 1);
                    gw = min(max(gw, 0), WW - 1);
                }
                const int ga = gh * WW + gw;
                const int c0 = ucg * 4;
                H2U ka, kc, va, vc;
                ka.h.x = (_Float16)kbp[(c0    ) * PLANE + ga];
                ka.h.y = (_Float16)kbp[(c0 + 1) * PLANE + ga];
                kc.h.x = (_Float16)kbp[(c0 + 2) * PLANE + ga];
                kc.h.y = (_Float16)kbp[(c0 + 3) * PLANE + ga];
                va.h.x = (_Float16)vbp[(c0    ) * PLANE + ga];
                va.h.y = (_Float16)vbp[(c0 + 1) * PLANE + ga];
                vc.h.x = (_Float16)vbp[(c0 + 2) * PLANE + ga];
                vc.h.y = (_Float16)vbp[(c0 + 3) * PLANE + ga];
                uint4 u4; u4.x = ka.u; u4.y = kc.u; u4.z = va.u; u4.w = vc.u;
                lds4[pix * PUNITS + ucg] = u4;
            }
        }
    }
    __syncthreads();

    // center unit index for (dy=0,dx=0); neighbor offsets fold to immediates
    const int lbase = ((py + RAD) * HS + (px + RAD)) * PUNITS + cg;

    float ssum = 0.f, o0 = 0.f, o1 = 0.f, o2 = 0.f, o3 = 0.f;
    if (ns == 0)
        nb_range<INTERIOR,  0, 25>(lds4, lbase, q01, q23, h, w, ssum, o0, o1, o2, o3);
    else
        nb_range<INTERIOR, 25, 49>(lds4, lbase, q01, q23, h, w, ssum, o0, o1, o2, o3);

    // merge the two neighbor-halves (lanes differ in bit 2)
    ssum += __shfl_xor(ssum, 4, 64);
    o0   += __shfl_xor(o0,   4, 64);
    o1   += __shfl_xor(o1,   4, 64);
    o2   += __shfl_xor(o2,   4, 64);
    o3   += __shfl_xor(o3,   4, 64);

    if (ns == 0) {
        const float inv = 1.0f / ssum;
        out[qoff]             = o0 * inv;
        out[qoff +     PLANE] = o1 * inv;
        out[qoff + 2 * PLANE] = o2 * inv;
        out[qoff + 3 * PLANE] = o3 * inv;
    }
}

__global__ __launch_bounds__(512, 8) void natten_ns8(
    const float* __restrict__ q, const float* __restrict__ k,
    const float* __restrict__ v, float* __restrict__ out)
{
    __shared__ __align__(16) uint4 lds4[HP * PUNITS];   // 15,680 B

    const int bid  = (int)blockIdx.x;
    const int slab = bid & 7;            // one (b,head) per XCD
    const int tile = bid >> 3;           // 0..143
    const int b = slab >> 2, head = slab & 3;
    const int ty = tile / TPD, tx = tile % TPD;
    const int h0 = ty * TS, w0 = tx * TS;

    const bool interior = (ty >= 1) && (ty <= TPD - 2) &&
                          (tx >= 1) && (tx <= TPD - 2);
    if (interior)
        tile_body<true >(q, k, v, out, lds4, b, head, h0, w0);
    else
        tile_body<false>(q, k, v, out, lds4, b, head, h0, w0);
}

extern "C" void kernel_launch(void* const* d_in, const int* in_sizes, int n_in,
                              void* d_out, int out_size, void* d_ws, size_t ws_size,
                              hipStream_t stream) {
    const float* q = (const float*)d_in[0];
    const float* k = (const float*)d_in[1];
    const float* v = (const float*)d_in[2];
    float* out = (float*)d_out;

    const int grid = BATCH * NHEADS * TILES;   // 1152
    natten_ns8<<<grid, 512, 0, stream>>>(q, k, v, out);
}

// Round 10
// 17.681 us; speedup vs baseline: 1.2387x; 1.2387x over previous
//
#include <hip/hip_runtime.h>

// Problem constants (from reference)
#define HH 96
#define WW 96
#define CH 64
#define NHEADS 4
#define DHEAD 16
#define BATCH 2
#define PLANE (HH * WW)

// MFMA row-tile geometry: block = 8 waves; wave = 1 row x 16 positions.
#define BROWS 8
#define BCOLS 16
#define HROWS (BROWS + 6)       // 14 halo rows
#define HCOLS (BCOLS + 6)       // 22 halo cols
#define KPITCH 20               // halfs per halo pixel in k_lds (16 + 4 pad)
#define KPIX (HROWS * HCOLS)    // 308
#define KPIXA 318               // +10 tail pixels (zeroed; covers A2 overrun)
#define VPITCH 24               // halfs per halo row in v_lds (22 + 2 zero)
#define VCH 344                 // halfs per channel in v_lds (14*24 + 8 pad)
#define TY_N (HH / BROWS)       // 12
#define TX_N (WW / BCOLS)       // 6

typedef _Float16 half4 __attribute__((ext_vector_type(4)));
typedef float f32x4 __attribute__((ext_vector_type(4)));

template <bool INTERIOR>
__device__ __forceinline__ void block_body(
    const float* __restrict__ q, const float* __restrict__ k,
    const float* __restrict__ v, float* __restrict__ out,
    _Float16* __restrict__ lk, _Float16* __restrict__ lv,
    int c0, int h0, int w0)
{
    const int tid = threadIdx.x;
    const half4 hz = {(_Float16)0.f, (_Float16)0.f, (_Float16)0.f, (_Float16)0.f};

    // ---- stage K halo, pixel-major [pix][16ch] fp16 (+ zero tail) ----
    for (int u = tid; u < KPIX * 4 + 50; u += 512) {
        if (u < KPIX * 4) {
            const int cg  = u & 3;
            const int pix = u >> 2;
            int gh = h0 - 3 + pix / HCOLS;
            int gw = w0 - 3 + pix % HCOLS;
            if constexpr (!INTERIOR) {
                gh = min(max(gh, 0), HH - 1);
                gw = min(max(gw, 0), WW - 1);
            }
            const float* kp = k + (size_t)(c0 + cg * 4) * PLANE + gh * WW + gw;
            half4 hv;
            hv.x = (_Float16)kp[0];
            hv.y = (_Float16)kp[PLANE];
            hv.z = (_Float16)kp[2 * PLANE];
            hv.w = (_Float16)kp[3 * PLANE];
            *(half4*)&lk[pix * KPITCH + cg * 4] = hv;
        } else {                      // zero pixels 308..317 (A2 overrun region)
            const int z  = u - KPIX * 4;          // 0..49
            const int px = KPIX + z / 5;
            const int c4 = (z % 5) * 4;
            *(half4*)&lk[px * KPITCH + c4] = hz;
        }
    }

    // ---- stage V halo, channel-major [16ch][row*24 + col] fp16 (+ zeros) ----
    for (int u = tid; u < 1376; u += 512) {
        if (u < 1344) {                           // 16ch * 14rows * 6segs
            const int seg = u % 6;
            const int row = (u / 6) % HROWS;
            const int c   = u / 84;
            int gh = h0 - 3 + row;
            if constexpr (!INTERIOR) gh = min(max(gh, 0), HH - 1);
            const float* vp = v + (size_t)(c0 + c) * PLANE + gh * WW;
            const int wc0 = seg * 4;
            half4 hv = hz;
#pragma unroll
            for (int e = 0; e < 4; ++e) {
                const int wc = wc0 + e;
                if (wc < HCOLS) {
                    int gw = w0 - 3 + wc;
                    if constexpr (!INTERIOR) gw = min(max(gw, 0), WW - 1);
                    hv[e] = (_Float16)vp[gw];
                }
            }
            *(half4*)&lv[c * VCH + row * VPITCH + wc0] = hv;
        } else {                                  // zero per-channel tail 336..343
            const int z = u - 1344;               // 0..31
            *(half4*)&lv[(z >> 1) * VCH + 336 + (z & 1) * 4] = hz;
        }
    }
    __syncthreads();

    // ---- compute: wave wid handles row h0+wid, positions w0..w0+15 ----
    const int lane = tid & 63;
    const int wid  = tid >> 6;
    const int lp   = lane & 15;      // p (QK-B col / C col), pixel j (QK-A row), channel c (PV-A row)
    const int lg   = lane >> 4;      // k-group selector
    const int h    = h0 + wid;

    const float QS = 0.25f * 1.4426950408889634f;  // 1/sqrt(16) * log2(e)
    const int qbase = (c0 + lg * 4) * PLANE + h * WW + w0 + lp;
    half4 qf;
    qf.x = (_Float16)(q[qbase] * QS);
    qf.y = (_Float16)(q[qbase + PLANE] * QS);
    qf.z = (_Float16)(q[qbase + 2 * PLANE] * QS);
    qf.w = (_Float16)(q[qbase + 3 * PLANE] * QS);

    f32x4 acc = {0.f, 0.f, 0.f, 0.f};
    float ssum = 0.f;

#pragma unroll
    for (int dy = 0; dy < 7; ++dy) {
        if constexpr (!INTERIOR) {
            if ((unsigned)(h + dy - 3) >= (unsigned)HH) continue;  // invalid row
        }
        const int r = wid + dy;                    // halo row index

        // QK: S^T[j][p] = K_pix[j][c] x Q[c][p]
        const half4 ka1 = *(const half4*)&lk[(r * HCOLS + lp) * KPITCH + lg * 4];
        const half4 ka2 = *(const half4*)&lk[(r * HCOLS + 16 + lp) * KPITCH + lg * 4];
        const f32x4 zz = {0.f, 0.f, 0.f, 0.f};
        f32x4 s1 = __builtin_amdgcn_mfma_f32_16x16x16f16(ka1, qf, zz, 0, 0, 0);
        f32x4 s2 = __builtin_amdgcn_mfma_f32_16x16x16f16(ka2, qf, zz, 0, 0, 0);

        // masked exp2 -> P fragments (C layout == B layout: direct feed)
        half4 p1, p2;
#pragma unroll
        for (int e = 0; e < 4; ++e) {
            const int j1 = lg * 4 + e;
            const int j2 = 16 + lg * 4 + e;
            bool ok1 = ((unsigned)(j1 - lp) < 7u);        // band: j in [p, p+6]
            bool ok2 = ((unsigned)(j2 - lp) < 7u);
            if constexpr (!INTERIOR) {
                ok1 = ok1 && ((unsigned)(w0 - 3 + j1) < (unsigned)WW);
                ok2 = ok2 && ((unsigned)(w0 - 3 + j2) < (unsigned)WW);
            }
            const float e1 = ok1 ? __builtin_amdgcn_exp2f(s1[e]) : 0.f;
            const float e2 = ok2 ? __builtin_amdgcn_exp2f(s2[e]) : 0.f;
            ssum += e1 + e2;
            p1[e] = (_Float16)e1;
            p2[e] = (_Float16)e2;
        }

        // PV: out^T[c][p] += V^T[c][j] x P[j][p]
        const half4 va1 = *(const half4*)&lv[lp * VCH + r * VPITCH + lg * 4];
        const half4 va2 = *(const half4*)&lv[lp * VCH + r * VPITCH + 16 + lg * 4];
        acc = __builtin_amdgcn_mfma_f32_16x16x16f16(va1, p1, acc, 0, 0, 0);
        acc = __builtin_amdgcn_mfma_f32_16x16x16f16(va2, p2, acc, 0, 0, 0);
    }

    // softmax denominator: reduce partial sums across the 4 lane-groups
    ssum += __shfl_xor(ssum, 16, 64);
    ssum += __shfl_xor(ssum, 32, 64);
    const float inv = 1.0f / ssum;

    // store: C rows c = lg*4 + r, col p = lp -> coalesced 16-dword runs
    const int obase = (c0 + lg * 4) * PLANE + h * WW + w0 + lp;
#pragma unroll
    for (int r = 0; r < 4; ++r)
        out[obase + r * PLANE] = acc[r] * inv;
}

__global__ __launch_bounds__(512, 4) void natten_mfma(
    const float* __restrict__ q, const float* __restrict__ k,
    const float* __restrict__ v, float* __restrict__ out)
{
    __shared__ __align__(16) _Float16 lk[KPIXA * KPITCH];  // 12,720 B
    __shared__ __align__(16) _Float16 lv[16 * VCH];        // 11,008 B

    const int bid  = (int)blockIdx.x;
    const int slab = bid & 7;               // one (b,head) per XCD
    const int t    = bid >> 3;              // 0..71
    const int b = slab >> 2, head = slab & 3;
    const int ty = t / TX_N, tx = t % TX_N;
    const int c0 = b * CH + head * DHEAD;
    const int h0 = ty * BROWS, w0 = tx * BCOLS;

    const bool interior = (ty >= 1) && (ty <= TY_N - 2) &&
                          (tx >= 1) && (tx <= TX_N - 2);
    if (interior)
        block_body<true >(q, k, v, out, lk, lv, c0, h0, w0);
    else
        block_body<false>(q, k, v, out, lk, lv, c0, h0, w0);
}

extern "C" void kernel_launch(void* const* d_in, const int* in_sizes, int n_in,
                              void* d_out, int out_size, void* d_ws, size_t ws_size,
                              hipStream_t stream) {
    const float* q = (const float*)d_in[0];
    const float* k = (const float*)d_in[1];
    const float* v = (const float*)d_in[2];
    float* out = (float*)d_out;

    const int grid = BATCH * NHEADS * TY_N * TX_N;   // 576
    natten_mfma<<<grid, 512, 0, stream>>>(q, k, v, out);
}

// Round 11
// 16.127 us; speedup vs baseline: 1.3580x; 1.0963x over previous
//
#include <hip/hip_runtime.h>

// Problem constants (from reference)
#define HH 96
#define WW 96
#define CH 64
#define NHEADS 4
#define DHEAD 16
#define BATCH 2
#define PLANE (HH * WW)

// MFMA row-tile geometry: block = 8 waves; wave = 1 row x 16 positions.
#define BROWS 8
#define BCOLS 16
#define HROWS (BROWS + 6)       // 14 halo rows
#define HCOLS (BCOLS + 6)       // 22 halo cols
#define KPITCH 20               // halfs per halo pixel in k_lds (16 + 4 pad)
#define KPIX (HROWS * HCOLS)    // 308
#define KPIXA 318               // +10 tail pixels (zeroed; covers A2 overrun)
#define VPITCH 24               // halfs per halo row in v_lds (22 + 2 zero pad)
#define VCH (HROWS * VPITCH + 8)// 344 halfs per channel (+8 zero tail)
#define TY_N (HH / BROWS)       // 12
#define TX_N (WW / BCOLS)       // 6

typedef _Float16 half4 __attribute__((ext_vector_type(4)));
typedef float f32x4 __attribute__((ext_vector_type(4)));
typedef _Float16 h2 __attribute__((ext_vector_type(2)));
union H2U { unsigned int u; h2 h; };

template <bool INTERIOR>
__device__ __forceinline__ void block_body(
    const float* __restrict__ q, const float* __restrict__ k,
    const float* __restrict__ v, float* __restrict__ out,
    _Float16* __restrict__ lk, _Float16* __restrict__ lv,
    int c0, int h0, int w0)
{
    const int tid = threadIdx.x;

    // ---- q fragment first (overlaps staging latency) ----
    const int lane = tid & 63;
    const int wid  = tid >> 6;
    const int lp   = lane & 15;
    const int lg   = lane >> 4;
    const int h    = h0 + wid;

    const float QS = 0.25f * 1.4426950408889634f;  // 1/sqrt(16) * log2(e)
    const int qbase = (c0 + lg * 4) * PLANE + h * WW + w0 + lp;
    half4 qf;
    qf.x = (_Float16)(q[qbase] * QS);
    qf.y = (_Float16)(q[qbase + PLANE] * QS);
    qf.z = (_Float16)(q[qbase + 2 * PLANE] * QS);
    qf.w = (_Float16)(q[qbase + 3 * PLANE] * QS);

    // ---- K staging: span = (row, ch-pair), 32 lanes sweep 22 cols ----
    // 112 spans = 14 rows x 8 ch-pairs; 16 spans/round x 7 rounds (exact).
    // Per load instr: 2 spans x 22 contiguous floats -> ~2 segments.
    {
        const int col = tid & 31;
        const int sp0 = tid >> 5;          // 0..15
#pragma unroll
        for (int r = 0; r < 7; ++r) {
            const int sid = r * 16 + sp0;  // 0..111
            const int row = sid >> 3;
            const int cp  = sid & 7;
            if (col < HCOLS) {
                int gh = h0 - 3 + row;
                int gw = w0 - 3 + col;
                if constexpr (!INTERIOR) {
                    gh = min(max(gh, 0), HH - 1);
                    gw = min(max(gw, 0), WW - 1);
                }
                const float* p0 = k + (size_t)(c0 + cp * 2) * PLANE + gh * WW + gw;
                H2U t;
                t.h.x = (_Float16)p0[0];
                t.h.y = (_Float16)p0[PLANE];
                *(h2*)&lk[(row * HCOLS + col) * KPITCH + cp * 2] = t.h;
            }
        }
    }

    // ---- V staging: span = (row, ch), 16 lanes x 2 contiguous cols ----
    // 224 spans = 14 rows x 16 ch; 32 spans/round x 7 rounds (exact).
    {
        const int l16  = tid & 15;
        const int sq0  = tid >> 4;         // 0..31
        const int col0 = l16 * 2;
#pragma unroll
        for (int r = 0; r < 7; ++r) {
            const int sid = r * 32 + sq0;  // 0..223
            const int row = sid >> 4;
            const int ch  = sid & 15;
            if (col0 <= HCOLS) {           // cols 0..21 data, 22 -> zero pad
                H2U t;
                if (col0 < HCOLS) {
                    int gh = h0 - 3 + row;
                    int ga = w0 - 3 + col0;
                    int gb = ga + 1;
                    if constexpr (!INTERIOR) {
                        gh = min(max(gh, 0), HH - 1);
                        ga = min(max(ga, 0), WW - 1);
                        gb = min(max(gb, 0), WW - 1);
                    }
                    const float* p0 = v + (size_t)(c0 + ch) * PLANE + gh * WW;
                    t.h.x = (_Float16)p0[ga];
                    t.h.y = (_Float16)p0[gb];
                } else {
                    t.u = 0;               // pad cols 22,23
                }
                *(h2*)&lv[ch * VCH + row * VPITCH + col0] = t.h;
            }
        }
    }

    // ---- zero tails (read by A2 fragments; must be finite/zero) ----
    {
        H2U z; z.u = 0;
        if (tid < 100)                      // K pixels 308..317 (200 halfs)
            *(h2*)&lk[KPIX * KPITCH + tid * 2] = z.h;
        if (tid < 64)                       // V per-channel tail halfs 336..343
            *(h2*)&lv[(tid >> 2) * VCH + 336 + (tid & 3) * 2] = z.h;
    }
    __syncthreads();

    // ---- compute: wave wid -> row h0+wid, positions w0..w0+15 ----
    f32x4 acc = {0.f, 0.f, 0.f, 0.f};
    float ssum = 0.f;

#pragma unroll
    for (int dy = 0; dy < 7; ++dy) {
        if constexpr (!INTERIOR) {
            if ((unsigned)(h + dy - 3) >= (unsigned)HH) continue;  // invalid row
        }
        const int r = wid + dy;                    // halo row index

        // QK: S^T[j][p] = K_pix[j][c] x Q[c][p]
        const half4 ka1 = *(const half4*)&lk[(r * HCOLS + lp) * KPITCH + lg * 4];
        const half4 ka2 = *(const half4*)&lk[(r * HCOLS + 16 + lp) * KPITCH + lg * 4];
        const f32x4 zz = {0.f, 0.f, 0.f, 0.f};
        f32x4 s1 = __builtin_amdgcn_mfma_f32_16x16x16f16(ka1, qf, zz, 0, 0, 0);
        f32x4 s2 = __builtin_amdgcn_mfma_f32_16x16x16f16(ka2, qf, zz, 0, 0, 0);

        // masked exp2 -> P fragments (C layout == B layout: direct feed)
        half4 p1, p2;
#pragma unroll
        for (int e = 0; e < 4; ++e) {
            const int j1 = lg * 4 + e;
            const int j2 = 16 + lg * 4 + e;
            bool ok1 = ((unsigned)(j1 - lp) < 7u);        // band: j in [p, p+6]
            bool ok2 = ((unsigned)(j2 - lp) < 7u);
            if constexpr (!INTERIOR) {
                ok1 = ok1 && ((unsigned)(w0 - 3 + j1) < (unsigned)WW);
                ok2 = ok2 && ((unsigned)(w0 - 3 + j2) < (unsigned)WW);
            }
            const float e1 = ok1 ? __builtin_amdgcn_exp2f(s1[e]) : 0.f;
            const float e2 = ok2 ? __builtin_amdgcn_exp2f(s2[e]) : 0.f;
            ssum += e1 + e2;
            p1[e] = (_Float16)e1;
            p2[e] = (_Float16)e2;
        }

        // PV: out^T[c][p] += V^T[c][j] x P[j][p]
        const half4 va1 = *(const half4*)&lv[lp * VCH + r * VPITCH + lg * 4];
        const half4 va2 = *(const half4*)&lv[lp * VCH + r * VPITCH + 16 + lg * 4];
        acc = __builtin_amdgcn_mfma_f32_16x16x16f16(va1, p1, acc, 0, 0, 0);
        acc = __builtin_amdgcn_mfma_f32_16x16x16f16(va2, p2, acc, 0, 0, 0);
    }

    // softmax denominator: reduce partial sums across the 4 lane-groups
    ssum += __shfl_xor(ssum, 16, 64);
    ssum += __shfl_xor(ssum, 32, 64);
    const float inv = 1.0f / ssum;

    // store: C rows c = lg*4 + e, col p = lp -> 4-segment coalesced
    const int obase = (c0 + lg * 4) * PLANE + h * WW + w0 + lp;
#pragma unroll
    for (int e = 0; e < 4; ++e)
        out[obase + e * PLANE] = acc[e] * inv;
}

__global__ __launch_bounds__(512, 4) void natten_mfma(
    const float* __restrict__ q, const float* __restrict__ k,
    const float* __restrict__ v, float* __restrict__ out)
{
    __shared__ __align__(16) _Float16 lk[KPIXA * KPITCH];  // 12,720 B
    __shared__ __align__(16) _Float16 lv[16 * VCH];        // 11,008 B

    const int bid  = (int)blockIdx.x;
    const int slab = bid & 7;               // one (b,head) per XCD
    const int t    = bid >> 3;              // 0..71
    const int b = slab >> 2, head = slab & 3;
    const int ty = t / TX_N, tx = t % TX_N;
    const int c0 = b * CH + head * DHEAD;
    const int h0 = ty * BROWS, w0 = tx * BCOLS;

    const bool interior = (ty >= 1) && (ty <= TY_N - 2) &&
                          (tx >= 1) && (tx <= TX_N - 2);
    if (interior)
        block_body<true >(q, k, v, out, lk, lv, c0, h0, w0);
    else
        block_body<false>(q, k, v, out, lk, lv, c0, h0, w0);
}

extern "C" void kernel_launch(void* const* d_in, const int* in_sizes, int n_in,
                              void* d_out, int out_size, void* d_ws, size_t ws_size,
                              hipStream_t stream) {
    const float* q = (const float*)d_in[0];
    const float* k = (const float*)d_in[1];
    const float* v = (const float*)d_in[2];
    float* out = (float*)d_out;

    const int grid = BATCH * NHEADS * TY_N * TX_N;   // 576
    natten_mfma<<<grid, 512, 0, stream>>>(q, k, v, out);
}

// Round 12
// 15.467 us; speedup vs baseline: 1.4159x; 1.0426x over previous
//
#include <hip/hip_runtime.h>

// Problem constants (from reference)
#define HH 96
#define WW 96
#define CH 64
#define NHEADS 4
#define DHEAD 16
#define BATCH 2
#define PLANE (HH * WW)

// MFMA row-tile geometry: block = 6 waves; wave = 1 row x 16 positions.
// Grid = 8 slabs x 96 tiles = 768 blocks = EXACTLY 3 blocks/CU (no tail).
#define BROWS 6
#define BCOLS 16
#define HROWS (BROWS + 6)       // 12 halo rows
#define HCOLS (BCOLS + 6)       // 22 halo cols
#define KPITCH 20               // halfs per halo pixel in k_lds (16 + 4 pad)
#define KPIX (HROWS * HCOLS)    // 264
#define KPIXA (KPIX + 10)       // 274: zero tail covers A2 fragment overrun
#define VPITCH 24               // halfs per halo row in v_lds (22 + 2 zero pad)
#define VCH (HROWS * VPITCH + 8)// 296 halfs per channel (+8 zero tail)
#define TY_N (HH / BROWS)       // 16
#define TX_N (WW / BCOLS)       // 6

typedef _Float16 half4 __attribute__((ext_vector_type(4)));
typedef float f32x4 __attribute__((ext_vector_type(4)));
typedef _Float16 h2 __attribute__((ext_vector_type(2)));
union H2U { unsigned int u; h2 h; };

template <bool INTERIOR>
__device__ __forceinline__ void block_body(
    const float* __restrict__ q, const float* __restrict__ k,
    const float* __restrict__ v, float* __restrict__ out,
    _Float16* __restrict__ lk, _Float16* __restrict__ lv,
    int c0, int h0, int w0)
{
    const int tid = threadIdx.x;        // 0..383

    // ---- q fragment first (overlaps staging latency) ----
    const int lane = tid & 63;
    const int wid  = tid >> 6;          // 0..5
    const int lp   = lane & 15;
    const int lg   = lane >> 4;
    const int h    = h0 + wid;

    const float QS = 0.25f * 1.4426950408889634f;  // 1/sqrt(16) * log2(e)
    const int qbase = (c0 + lg * 4) * PLANE + h * WW + w0 + lp;
    half4 qf;
    qf.x = (_Float16)(q[qbase] * QS);
    qf.y = (_Float16)(q[qbase + PLANE] * QS);
    qf.z = (_Float16)(q[qbase + 2 * PLANE] * QS);
    qf.w = (_Float16)(q[qbase + 3 * PLANE] * QS);

    // ---- K staging: span = (row, ch-pair); 32 lanes sweep 22 cols ----
    // 96 spans = 12 rows x 8 ch-pairs; 12 span-slots x 8 rounds (exact).
    {
        const int col = tid & 31;
        const int sp0 = tid >> 5;          // 0..11
#pragma unroll 2
        for (int r = 0; r < 8; ++r) {
            const int sid = r * 12 + sp0;  // 0..95
            const int row = sid >> 3;
            const int cp  = sid & 7;
            if (col < HCOLS) {
                int gh = h0 - 3 + row;
                int gw = w0 - 3 + col;
                if constexpr (!INTERIOR) {
                    gh = min(max(gh, 0), HH - 1);
                    gw = min(max(gw, 0), WW - 1);
                }
                const float* p0 = k + (size_t)(c0 + cp * 2) * PLANE + gh * WW + gw;
                H2U t;
                t.h.x = (_Float16)p0[0];
                t.h.y = (_Float16)p0[PLANE];
                *(h2*)&lk[(row * HCOLS + col) * KPITCH + cp * 2] = t.h;
            }
        }
    }

    // ---- V staging: span = (row, ch); 16 lanes x 2 contiguous cols ----
    // 192 spans = 12 rows x 16 ch; 24 span-slots x 8 rounds (exact).
    {
        const int l16  = tid & 15;
        const int sq0  = tid >> 4;         // 0..23
        const int col0 = l16 * 2;
#pragma unroll 2
        for (int r = 0; r < 8; ++r) {
            const int sid = r * 24 + sq0;  // 0..191
            const int row = sid >> 4;
            const int ch  = sid & 15;
            if (col0 <= HCOLS) {           // cols 0..21 data; 22 -> zero pad
                H2U t;
                if (col0 < HCOLS) {
                    int gh = h0 - 3 + row;
                    int ga = w0 - 3 + col0;
                    int gb = ga + 1;
                    if constexpr (!INTERIOR) {
                        gh = min(max(gh, 0), HH - 1);
                        ga = min(max(ga, 0), WW - 1);
                        gb = min(max(gb, 0), WW - 1);
                    }
                    const float* p0 = v + (size_t)(c0 + ch) * PLANE + gh * WW;
                    t.h.x = (_Float16)p0[ga];
                    t.h.y = (_Float16)p0[gb];
                } else {
                    t.u = 0;               // pad cols 22,23
                }
                *(h2*)&lv[ch * VCH + row * VPITCH + col0] = t.h;
            }
        }
    }

    // ---- zero tails (read by A2 fragments; must be finite) ----
    {
        H2U z; z.u = 0;
        if (tid < 100)                      // K pixels 264..273 (200 halfs)
            *(h2*)&lk[KPIX * KPITCH + tid * 2] = z.h;
        if (tid < 64)                       // V per-channel tail halfs 288..295
            *(h2*)&lv[(tid >> 2) * VCH + 288 + (tid & 3) * 2] = z.h;
    }
    __syncthreads();

    // ---- hoisted band/edge masks (loop-invariant over dy) ----
    bool ok1[4], ok2[4];
#pragma unroll
    for (int e = 0; e < 4; ++e) {
        const int j1 = lg * 4 + e;
        const int j2 = 16 + j1;
        ok1[e] = ((unsigned)(j1 - lp) < 7u);     // band: j in [p, p+6]
        ok2[e] = ((unsigned)(j2 - lp) < 7u);
        if constexpr (!INTERIOR) {
            ok1[e] = ok1[e] && ((unsigned)(w0 - 3 + j1) < (unsigned)WW);
            ok2[e] = ok2[e] && ((unsigned)(w0 - 3 + j2) < (unsigned)WW);
        }
    }

    // ---- compute: wave wid -> row h0+wid, positions w0..w0+15 ----
    f32x4 acc = {0.f, 0.f, 0.f, 0.f};
    float ssA = 0.f, ssB = 0.f;

#pragma unroll
    for (int dy = 0; dy < 7; ++dy) {
        if constexpr (!INTERIOR) {
            if ((unsigned)(h + dy - 3) >= (unsigned)HH) continue;  // invalid row
        }
        const int r = wid + dy;                    // halo row index

        // QK: S^T[j][p] = K_pix[j][c] x Q[c][p]
        const half4 ka1 = *(const half4*)&lk[(r * HCOLS + lp) * KPITCH + lg * 4];
        const half4 ka2 = *(const half4*)&lk[(r * HCOLS + 16 + lp) * KPITCH + lg * 4];
        const f32x4 zz = {0.f, 0.f, 0.f, 0.f};
        f32x4 s1 = __builtin_amdgcn_mfma_f32_16x16x16f16(ka1, qf, zz, 0, 0, 0);
        f32x4 s2 = __builtin_amdgcn_mfma_f32_16x16x16f16(ka2, qf, zz, 0, 0, 0);

        // masked exp2 -> P fragments (C layout == B layout: direct feed)
        half4 p1, p2;
#pragma unroll
        for (int e = 0; e < 4; ++e) {
            const float e1 = ok1[e] ? __builtin_amdgcn_exp2f(s1[e]) : 0.f;
            const float e2 = ok2[e] ? __builtin_amdgcn_exp2f(s2[e]) : 0.f;
            ssA += e1;
            ssB += e2;
            p1[e] = (_Float16)e1;
            p2[e] = (_Float16)e2;
        }

        // PV: out^T[c][p] += V^T[c][j] x P[j][p]
        const half4 va1 = *(const half4*)&lv[lp * VCH + r * VPITCH + lg * 4];
        const half4 va2 = *(const half4*)&lv[lp * VCH + r * VPITCH + 16 + lg * 4];
        acc = __builtin_amdgcn_mfma_f32_16x16x16f16(va1, p1, acc, 0, 0, 0);
        acc = __builtin_amdgcn_mfma_f32_16x16x16f16(va2, p2, acc, 0, 0, 0);
    }

    // softmax denominator: reduce partial sums across the 4 lane-groups
    float ssum = ssA + ssB;
    ssum += __shfl_xor(ssum, 16, 64);
    ssum += __shfl_xor(ssum, 32, 64);
    const float inv = 1.0f / ssum;

    // store: C rows c = lg*4 + e, col p = lp -> 4-segment coalesced
    const int obase = (c0 + lg * 4) * PLANE + h * WW + w0 + lp;
#pragma unroll
    for (int e = 0; e < 4; ++e)
        out[obase + e * PLANE] = acc[e] * inv;
}

__global__ __launch_bounds__(384)
__attribute__((amdgpu_waves_per_eu(8)))
void natten_mfma6(
    const float* __restrict__ q, const float* __restrict__ k,
    const float* __restrict__ v, float* __restrict__ out)
{
    __shared__ __align__(16) _Float16 lk[KPIXA * KPITCH];  // 10,960 B
    __shared__ __align__(16) _Float16 lv[16 * VCH];        //  9,472 B

    const int bid  = (int)blockIdx.x;
    const int slab = bid & 7;               // one (b,head) per XCD
    const int t    = bid >> 3;              // 0..95
    const int b = slab >> 2, head = slab & 3;
    const int ty = t / TX_N, tx = t % TX_N;
    const int c0 = b * CH + head * DHEAD;
    const int h0 = ty * BROWS, w0 = tx * BCOLS;

    const bool interior = (ty >= 1) && (ty <= TY_N - 2) &&
                          (tx >= 1) && (tx <= TX_N - 2);
    if (interior)
        block_body<true >(q, k, v, out, lk, lv, c0, h0, w0);
    else
        block_body<false>(q, k, v, out, lk, lv, c0, h0, w0);
}

extern "C" void kernel_launch(void* const* d_in, const int* in_sizes, int n_in,
                              void* d_out, int out_size, void* d_ws, size_t ws_size,
                              hipStream_t stream) {
    const float* q = (const float*)d_in[0];
    const float* k = (const float*)d_in[1];
    const float* v = (const float*)d_in[2];
    float* out = (float*)d_out;

    const int grid = BATCH * NHEADS * TY_N * TX_N;   // 768
    natten_mfma6<<<grid, 384, 0, stream>>>(q, k, v, out);
}